// Round 1
// baseline (8490.680 us; speedup 1.0000x reference)
//
#include <hip/hip_runtime.h>
#include <hip/hip_bf16.h>
#include <cmath>

#define DEV __device__ __forceinline__

constexpr int B_ = 8, S_ = 512, IN_ = 64, D_ = 512, L_ = 4;
constexpr int DI_ = 1024, DCONV_ = 4, DTR_ = 32;
constexpr int ROWS = B_ * S_;  // 4096

// ---------------- workspace arena (bytes) ----------------
constexpr size_t MB = 1ull << 20;
constexpr size_t OFF_X    = 0;              // x_cur   (4096,512)  8MB
constexpr size_t OFF_XN   = OFF_X   + 8*MB; // xn/pre  (4096,512)  8MB
constexpr size_t OFF_XZ   = OFF_XN  + 8*MB; // xz      (4096,2048) 32MB
constexpr size_t OFF_XM   = OFF_XZ  + 32*MB;// xm      (4096,1024) 16MB
constexpr size_t OFF_DT   = OFF_XM  + 16*MB;// dt      (4096,1024) 16MB
constexpr size_t OFF_XDBL = OFF_DT  + 16*MB;// x_dbl   (4096,64)   1MB
constexpr size_t OFF_YG   = OFF_XDBL+ 1*MB; // y_gated (4096,1024) 16MB
constexpr size_t OFF_MO   = OFF_YG  + 16*MB;// mamba_o (4096,512)  8MB
constexpr size_t OFF_WINT = OFF_MO  + 8*MB; // WinT    (512,64)    128KB
constexpr size_t OFF_MEAN = OFF_WINT+ 128*1024; // xmean (8,512)   16KB
constexpr size_t OFF_BASIS= OFF_XZ;         // basis (4096,4096) 64MB, aliases xz+xm+dt (dead by then)

// ---------------- math helpers ----------------
DEV float siluf(float x){ return x / (1.f + __expf(-x)); }
DEV float softplusf(float x){ return fmaxf(x, 0.f) + log1pf(__expf(-fabsf(x))); }

DEV void bspline8(float x, float* bb){
  const float h = 0.4f, g0 = -2.2f;
  float b0[11];
#pragma unroll
  for (int j = 0; j < 11; ++j){
    float gj  = g0 + h * j;
    float gj1 = g0 + h * (j + 1);
    b0[j] = (x >= gj && x < gj1) ? 1.f : 0.f;
  }
#pragma unroll
  for (int p = 1; p <= 3; ++p){
    float inv = 1.f / (h * p);
#pragma unroll
    for (int j = 0; j + p < 11; ++j){
      float gj  = g0 + h * j;
      float gip = g0 + h * (j + p + 1);
      b0[j] = (x - gj) * inv * b0[j] + (gip - x) * inv * b0[j + 1];
    }
  }
#pragma unroll
  for (int c = 0; c < 8; ++c) bb[c] = b0[c];
}

// ---------------- tiled f32 NT GEMM: C[m,n] = sum_k A[m,k]*W[n,k] ----------------
// EPI: 0 = store, 1 = C += acc (residual accumulate), 2 = softplus(acc + bias[n])
template<bool SILU_A, int EPI>
__global__ __launch_bounds__(256)
void gemm_nt(const float* __restrict__ A, int lda,
             const float* __restrict__ W, int ldw,
             float* __restrict__ C, int ldc,
             const float* __restrict__ bias, int K)
{
  __shared__ float As[16][68];  // [k][m], pad 68 keeps b128 alignment + kills store conflicts
  __shared__ float Ws[16][68];
  const int tid = threadIdx.x;
  const int m0 = blockIdx.y * 64, n0 = blockIdx.x * 64;
  const int lr = tid >> 2, lc = (tid & 3) * 4;
  const float* Ap = A + (size_t)(m0 + lr) * lda + lc;
  const float* Wp = W + (size_t)(n0 + lr) * ldw + lc;
  const int tx = tid & 15, ty = tid >> 4;
  float acc[4][4] = {};
  for (int k0 = 0; k0 < K; k0 += 16){
    float4 a = *(const float4*)(Ap + k0);
    float4 w = *(const float4*)(Wp + k0);
    if (SILU_A){ a.x = siluf(a.x); a.y = siluf(a.y); a.z = siluf(a.z); a.w = siluf(a.w); }
    __syncthreads();
    As[lc+0][lr] = a.x; As[lc+1][lr] = a.y; As[lc+2][lr] = a.z; As[lc+3][lr] = a.w;
    Ws[lc+0][lr] = w.x; Ws[lc+1][lr] = w.y; Ws[lc+2][lr] = w.z; Ws[lc+3][lr] = w.w;
    __syncthreads();
#pragma unroll
    for (int k = 0; k < 16; ++k){
      float4 av = *(const float4*)&As[k][ty*4];
      float4 wv = *(const float4*)&Ws[k][tx*4];
      acc[0][0] += av.x*wv.x; acc[0][1] += av.x*wv.y; acc[0][2] += av.x*wv.z; acc[0][3] += av.x*wv.w;
      acc[1][0] += av.y*wv.x; acc[1][1] += av.y*wv.y; acc[1][2] += av.y*wv.z; acc[1][3] += av.y*wv.w;
      acc[2][0] += av.z*wv.x; acc[2][1] += av.z*wv.y; acc[2][2] += av.z*wv.z; acc[2][3] += av.z*wv.w;
      acc[3][0] += av.w*wv.x; acc[3][1] += av.w*wv.y; acc[3][2] += av.w*wv.z; acc[3][3] += av.w*wv.w;
    }
  }
#pragma unroll
  for (int i = 0; i < 4; ++i){
    float* Crow = C + (size_t)(m0 + ty*4 + i) * ldc + n0 + tx*4;
    float4 r = {acc[i][0], acc[i][1], acc[i][2], acc[i][3]};
    if (EPI == 1){
      float4 c0 = *(const float4*)Crow;
      r.x += c0.x; r.y += c0.y; r.z += c0.z; r.w += c0.w;
    } else if (EPI == 2){
      const float* bp = bias + n0 + tx*4;
      r.x = softplusf(r.x + bp[0]); r.y = softplusf(r.y + bp[1]);
      r.z = softplusf(r.z + bp[2]); r.w = softplusf(r.w + bp[3]);
    }
    *(float4*)Crow = r;
  }
}

// ---------------- Win transpose (64,512) -> (512,64) ----------------
__global__ __launch_bounds__(256)
void transpose_win(const float* __restrict__ Win, float* __restrict__ WinT)
{
  int idx = blockIdx.x * 256 + threadIdx.x;  // 32768
  int n = idx >> 6, k = idx & 63;
  WinT[idx] = Win[(size_t)k * 512 + n];
}

// ---------------- liquid RNN scan: one 1024-thread wg per batch ----------------
// h' = h + (tanh(pre_t + h@Wrec + b) - h) / (softplus(tau)+0.1)
__global__ __launch_bounds__(1024)
void liquid_scan(const float* __restrict__ pre, const float* __restrict__ Wrec,
                 const float* __restrict__ bias, const float* __restrict__ tau,
                 float* __restrict__ xout)
{
  __shared__ float h[512];
  __shared__ float partial[8][512];
  const int b = blockIdx.x, tid = threadIdx.x;
  const int og = (tid & 127) * 4;   // 4 consecutive outputs
  const int ks = tid >> 7;          // 8-way K-split, 64 k each
  float tau_inv = 0.f, bo = 0.f;
  if (tid < 512){
    tau_inv = 1.f / (softplusf(tau[tid]) + 0.1f);
    bo = bias[tid];
    h[tid] = 0.f;
  }
  const float* preb = pre + (size_t)b * S_ * 512;
  float* xb = xout + (size_t)b * S_ * 512;
  const float* Wbase = Wrec + (size_t)(ks * 64) * 512 + og;
  __syncthreads();
  for (int t = 0; t < S_; ++t){
    float ax = 0.f, ay = 0.f, az = 0.f, aw = 0.f;
#pragma unroll 4
    for (int k = 0; k < 64; k += 4){
      float4 h4 = *(const float4*)&h[ks*64 + k];
      float4 w;
      w = *(const float4*)(Wbase + (size_t)(k+0)*512); ax += h4.x*w.x; ay += h4.x*w.y; az += h4.x*w.z; aw += h4.x*w.w;
      w = *(const float4*)(Wbase + (size_t)(k+1)*512); ax += h4.y*w.x; ay += h4.y*w.y; az += h4.y*w.z; aw += h4.y*w.w;
      w = *(const float4*)(Wbase + (size_t)(k+2)*512); ax += h4.z*w.x; ay += h4.z*w.y; az += h4.z*w.z; aw += h4.z*w.w;
      w = *(const float4*)(Wbase + (size_t)(k+3)*512); ax += h4.w*w.x; ay += h4.w*w.y; az += h4.w*w.z; aw += h4.w*w.w;
    }
    float4 pr = {ax, ay, az, aw};
    *(float4*)&partial[ks][og] = pr;
    __syncthreads();
    if (tid < 512){
      float s = partial[0][tid] + partial[1][tid] + partial[2][tid] + partial[3][tid]
              + partial[4][tid] + partial[5][tid] + partial[6][tid] + partial[7][tid];
      s += preb[(size_t)t*512 + tid] + bo;
      float act = tanhf(s);
      float hv = h[tid];
      hv += (act - hv) * tau_inv;
      h[tid] = hv;
      xb[(size_t)t*512 + tid] = hv;
    }
    __syncthreads();
  }
}

// ---------------- causal depthwise conv1d (k=4) + bias + SiLU ----------------
__global__ __launch_bounds__(256)
void conv_silu(const float* __restrict__ xz, const float* __restrict__ cw,
               const float* __restrict__ cb, float* __restrict__ xm)
{
  int idx = blockIdx.x * 256 + threadIdx.x;   // over ROWS*DI
  int d = idx & 1023;
  int bs = idx >> 10;
  int t = bs & 511;
  const float* p = xz + (size_t)bs * 2048 + d;  // xm part = first 1024 cols
  float4 w = *(const float4*)(cw + d*4);
  float acc = cb[d] + w.w * p[0];
  if (t >= 1) acc += w.z * p[-2048];
  if (t >= 2) acc += w.y * p[-2*2048];
  if (t >= 3) acc += w.x * p[-3*2048];
  xm[idx] = siluf(acc);
}

// ---------------- fused mamba selective scan + D-skip + z-gating ----------------
// thread pair (lane, lane+32) covers one channel d, 8 states each
__global__ __launch_bounds__(256)
void mamba_scan(const float* __restrict__ dt, const float* __restrict__ xm,
                const float* __restrict__ xdbl, const float* __restrict__ xz,
                const float* __restrict__ A_log, const float* __restrict__ Dp,
                float* __restrict__ yg)
{
  const int tid = threadIdx.x;
  const int wave = tid >> 6, lane = tid & 63;
  const int half = lane >> 5, dl = lane & 31;
  const int d = blockIdx.x * 128 + wave * 32 + dl;
  const int b = blockIdx.y;
  float A[8];
  {
    float4 a0 = *(const float4*)(A_log + (size_t)d*16 + half*8);
    float4 a1 = *(const float4*)(A_log + (size_t)d*16 + half*8 + 4);
    A[0] = -__expf(a0.x); A[1] = -__expf(a0.y); A[2] = -__expf(a0.z); A[3] = -__expf(a0.w);
    A[4] = -__expf(a1.x); A[5] = -__expf(a1.y); A[6] = -__expf(a1.z); A[7] = -__expf(a1.w);
  }
  const float Dv = Dp[d];
  float h[8] = {0,0,0,0,0,0,0,0};
  const size_t rb = (size_t)b * S_;
  const float* dtp = dt + rb*1024 + d;
  const float* xmp = xm + rb*1024 + d;
  const float* zp  = xz + rb*2048 + 1024 + d;
  const float* bcp = xdbl + rb*64 + 32 + half*8;
  const float* ccp = xdbl + rb*64 + 48 + half*8;
  float* yp = yg + rb*1024 + d;
  for (int t = 0; t < S_; ++t){
    float dtv = dtp[(size_t)t*1024];
    float xv  = xmp[(size_t)t*1024];
    float4 b0 = *(const float4*)(bcp + (size_t)t*64);
    float4 b1 = *(const float4*)(bcp + (size_t)t*64 + 4);
    float4 c0 = *(const float4*)(ccp + (size_t)t*64);
    float4 c1 = *(const float4*)(ccp + (size_t)t*64 + 4);
    float Bv[8] = {b0.x,b0.y,b0.z,b0.w,b1.x,b1.y,b1.z,b1.w};
    float Cv[8] = {c0.x,c0.y,c0.z,c0.w,c1.x,c1.y,c1.z,c1.w};
    float cbu = dtv * xv;
    float y = 0.f;
#pragma unroll
    for (int n = 0; n < 8; ++n){
      float da = __expf(dtv * A[n]);
      h[n] = da * h[n] + cbu * Bv[n];
      y += h[n] * Cv[n];
    }
    y += __shfl_xor(y, 32);
    if (half == 0){
      float zv = zp[(size_t)t*2048];
      yp[(size_t)t*1024] = (y + Dv * xv) * siluf(zv);
    }
  }
}

// ---------------- LayerNorm over last dim (512), one wg per row ----------------
__global__ __launch_bounds__(256)
void layernorm_k(const float* __restrict__ x, const float* __restrict__ g,
                 const float* __restrict__ b, float* __restrict__ y)
{
  __shared__ float red[8];
  const int row = blockIdx.x, tid = threadIdx.x;
  const float* xr = x + (size_t)row * 512;
  float2 v = *(const float2*)(xr + tid*2);
  float s = v.x + v.y;
#pragma unroll
  for (int o = 32; o; o >>= 1) s += __shfl_xor(s, o);
  if ((tid & 63) == 0) red[tid >> 6] = s;
  __syncthreads();
  float mean = (red[0] + red[1] + red[2] + red[3]) * (1.f/512.f);
  float dx = v.x - mean, dy = v.y - mean;
  float q = dx*dx + dy*dy;
#pragma unroll
  for (int o = 32; o; o >>= 1) q += __shfl_xor(q, o);
  if ((tid & 63) == 0) red[4 + (tid >> 6)] = q;
  __syncthreads();
  float var = (red[4] + red[5] + red[6] + red[7]) * (1.f/512.f);
  float rstd = rsqrtf(var + 1e-5f);
  float2 gg = *(const float2*)(g + tid*2);
  float2 bb = *(const float2*)(b + tid*2);
  float2 o2;
  o2.x = dx*rstd*gg.x + bb.x;
  o2.y = dy*rstd*gg.y + bb.y;
  *(float2*)(y + (size_t)row*512 + tid*2) = o2;
}

// ---------------- B-spline basis: (4096,512) -> (4096,512,8) ----------------
__global__ __launch_bounds__(256)
void bspline_kernel(const float* __restrict__ xin, float* __restrict__ basis)
{
  int idx = blockIdx.x * 256 + threadIdx.x;   // ROWS*512
  float x = xin[idx];
  float bb[8];
  bspline8(x, bb);
  float4 lo = {bb[0], bb[1], bb[2], bb[3]};
  float4 hi = {bb[4], bb[5], bb[6], bb[7]};
  float4* o = (float4*)(basis + (size_t)idx * 8);
  o[0] = lo; o[1] = hi;
}

// ---------------- mean over S ----------------
__global__ __launch_bounds__(512)
void mean_over_s(const float* __restrict__ x, float* __restrict__ out)
{
  int b = blockIdx.x, d = threadIdx.x;
  const float* p = x + (size_t)b*S_*512 + d;
  float s = 0.f;
  for (int t = 0; t < S_; ++t) s += p[(size_t)t*512];
  out[b*512 + d] = s * (1.f/512.f);
}

// ---------------- classifier KAN: (8,512) -> (8,10) ----------------
__global__ __launch_bounds__(64)
void cls_kan(const float* __restrict__ xmean, const float* __restrict__ bw,
             const float* __restrict__ sw, float* __restrict__ out)
{
  int o = blockIdx.x % 10, b = blockIdx.x / 10;
  int lane = threadIdx.x;
  float acc = 0.f;
  for (int i = lane; i < 512; i += 64){
    float xv = xmean[b*512 + i];
    acc += siluf(xv) * bw[o*512 + i];
    float bb[8]; bspline8(xv, bb);
    const float* sp = sw + ((size_t)(o*512 + i)) * 8;
#pragma unroll
    for (int c = 0; c < 8; ++c) acc += bb[c] * sp[c];
  }
#pragma unroll
  for (int off = 32; off; off >>= 1) acc += __shfl_xor(acc, off);
  if (lane == 0) out[b*10 + o] = acc;
}

// ---------------- launch ----------------
extern "C" void kernel_launch(void* const* d_in, const int* in_sizes, int n_in,
                              void* d_out, int out_size, void* d_ws, size_t ws_size,
                              hipStream_t stream)
{
  const float* x_in    = (const float*)d_in[0];
  const float* lq_Win  = (const float*)d_in[1];
  const float* lq_Wrec = (const float*)d_in[2];
  const float* lq_b    = (const float*)d_in[3];
  const float* lq_tau  = (const float*)d_in[4];
  const float* ln_g    = (const float*)d_in[5];
  const float* ln_bi   = (const float*)d_in[6];
  const float* in_proj = (const float*)d_in[7];
  const float* conv_w  = (const float*)d_in[8];
  const float* conv_b  = (const float*)d_in[9];
  const float* x_proj  = (const float*)d_in[10];
  const float* dt_w    = (const float*)d_in[11];
  const float* dt_b    = (const float*)d_in[12];
  const float* A_log   = (const float*)d_in[13];
  const float* Dp      = (const float*)d_in[14];
  const float* out_w   = (const float*)d_in[15];
  const float* kb_w    = (const float*)d_in[16];
  const float* ks_w    = (const float*)d_in[17];
  const float* fn_g    = (const float*)d_in[18];
  const float* fn_b    = (const float*)d_in[19];
  const float* cb_w    = (const float*)d_in[20];
  const float* cs_w    = (const float*)d_in[21];
  float* out = (float*)d_out;

  char* ws = (char*)d_ws;
  float* xcur  = (float*)(ws + OFF_X);
  float* xn    = (float*)(ws + OFF_XN);
  float* xz    = (float*)(ws + OFF_XZ);
  float* xm    = (float*)(ws + OFF_XM);
  float* dtb   = (float*)(ws + OFF_DT);
  float* xdbl  = (float*)(ws + OFF_XDBL);
  float* yg    = (float*)(ws + OFF_YG);
  float* mo    = (float*)(ws + OFF_MO);
  float* wint  = (float*)(ws + OFF_WINT);
  float* xmean = (float*)(ws + OFF_MEAN);
  float* basis = (float*)(ws + OFF_BASIS);

  // liquid projection: pre = x @ Win  (via WinT so the GEMM stays NT)
  transpose_win<<<128, 256, 0, stream>>>(lq_Win, wint);
  gemm_nt<false,0><<<dim3(D_/64, ROWS/64), 256, 0, stream>>>(x_in, IN_, wint, IN_, xn, D_, nullptr, IN_);
  liquid_scan<<<B_, 1024, 0, stream>>>(xn, lq_Wrec, lq_b, lq_tau, xcur);

  for (int l = 0; l < L_; ++l){
    layernorm_k<<<ROWS, 256, 0, stream>>>(xcur, ln_g + l*D_, ln_bi + l*D_, xn);
    gemm_nt<false,0><<<dim3(2*DI_/64, ROWS/64), 256, 0, stream>>>(
        xn, D_, in_proj + (size_t)l*2*DI_*D_, D_, xz, 2*DI_, nullptr, D_);
    conv_silu<<<ROWS*DI_/256, 256, 0, stream>>>(xz, conv_w + l*DI_*DCONV_, conv_b + l*DI_, xm);
    gemm_nt<false,0><<<dim3(1, ROWS/64), 256, 0, stream>>>(
        xm, DI_, x_proj + (size_t)l*64*DI_, DI_, xdbl, 64, nullptr, DI_);
    gemm_nt<false,2><<<dim3(DI_/64, ROWS/64), 256, 0, stream>>>(
        xdbl, 64, dt_w + (size_t)l*DI_*DTR_, DTR_, dtb, DI_, dt_b + l*DI_, DTR_);
    mamba_scan<<<dim3(DI_/128, B_), 256, 0, stream>>>(
        dtb, xm, xdbl, xz, A_log + (size_t)l*DI_*16, Dp + l*DI_, yg);
    gemm_nt<false,0><<<dim3(D_/64, ROWS/64), 256, 0, stream>>>(
        yg, DI_, out_w + (size_t)l*D_*DI_, DI_, mo, D_, nullptr, DI_);
    bspline_kernel<<<ROWS*D_/256, 256, 0, stream>>>(mo, basis);
    gemm_nt<true,1><<<dim3(D_/64, ROWS/64), 256, 0, stream>>>(
        mo, D_, kb_w + (size_t)l*D_*D_, D_, xcur, D_, nullptr, D_);
    gemm_nt<false,1><<<dim3(D_/64, ROWS/64), 256, 0, stream>>>(
        basis, D_*8, ks_w + (size_t)l*D_*D_*8, D_*8, xcur, D_, nullptr, D_*8);
  }

  layernorm_k<<<ROWS, 256, 0, stream>>>(xcur, fn_g, fn_b, xn);
  mean_over_s<<<B_, 512, 0, stream>>>(xn, xmean);
  cls_kan<<<B_*10, 64, 0, stream>>>(xmean, cb_w, cs_w, out);
}